// Round 10
// baseline (257.309 us; speedup 1.0000x reference)
//
#include <hip/hip_runtime.h>

// VEConv: E=800000, N=50000, RBF=100, D=64. E % 64 == 0 (12500 blocks).
// Round 10: dense-staging test. All r5/r7/r9 variants pinned at ~2.45 TB/s
// effective memory throughput regardless of occupancy/atomics; the remaining
// structural difference vs the 6.3 TB/s copy ubench is per-instruction address
// divergence (16B lane-pieces at 400B row stride + gathers). This round makes
// every rbf/edge_f read a dense contiguous 1KB-per-instruction burst:
//   - 64-edge blocks; rbf tile (25.6KB) + ef tile (16KB) are gapless spans,
//     loaded f32x4-coalesced, converted to bf16 in transit, stored to LDS
//   - MFMA B-fragments read from LDS (rbf row padded to 208B for b128
//     alignment; ef XOR-swizzled) -- r1-style, but staging is now coalesced
//   - r7 epilogue: contiguous-dim f32 atomic scatter (byte-minimal: 551 MB)
//   - 60.8 KB LDS -> 2 blocks/CU; block alternation overlaps stage/compute
#define RBF_DIM 100

typedef __attribute__((ext_vector_type(8))) short bf16x8;
typedef __attribute__((ext_vector_type(4))) float f32x4;

__device__ __forceinline__ unsigned short f2bf_sw(float f) {
    union { float f; unsigned int u; } v; v.f = f;
    unsigned int r = (v.u + 0x7FFFu + ((v.u >> 16) & 1u)) >> 16;
    return (unsigned short)r;
}
// hardware packed cvt: lo16 = bf16(x), hi16 = bf16(y), RNE
__device__ __forceinline__ unsigned int cvtpk(float x, float y) {
    unsigned int r;
    asm("v_cvt_pk_bf16_f32 %0, %1, %2" : "=v"(r) : "v"(x), "v"(y));
    return r;
}

// ---- pre-kernel: weights as bf16 MFMA fragments, dump order (unchanged) ----
__global__ void prep_weights(const float* __restrict__ W1, const float* __restrict__ b1,
                             const float* __restrict__ W2, const float* __restrict__ W3,
                             unsigned short* __restrict__ ws) {
    for (int e = threadIdx.x; e < 32 * 64 * 8; e += 256) {
        int f = e >> 9;
        int lane = (e >> 3) & 63;
        int j = e & 7;
        int l15 = lane & 15, g = lane >> 4;
        float v;
        if (f < 16) {
            int t4 = f >> 2, ks = f & 3;
            int k = 32 * ks + 8 * g + j, o = 16 * t4 + l15;
            v = (k < RBF_DIM) ? W1[k * 64 + o] : ((k == RBF_DIM) ? b1[o] : 0.0f);
        } else if (f < 24) {
            int q = f - 16, t4 = q >> 1, ks = q & 1;
            int k = 32 * ks + 8 * g + j, o = 16 * t4 + l15;
            v = W2[k * 64 + o];
        } else {
            int q = f - 24, t4 = q >> 1, ks = q & 1;
            int k = 32 * ks + 8 * g + j, o = 16 * t4 + l15;
            v = W3[k * 64 + o];
        }
        ws[e] = f2bf_sw(v);
    }
}

// ---- main fused kernel: 64 edges/block, 4 waves x 16 edges ----
__global__ __launch_bounds__(256, 2)
void veconv_main(const float* __restrict__ rbf, const float* __restrict__ edge_f,
                 const float* __restrict__ node,
                 const float* __restrict__ b2, const float* __restrict__ b3,
                 const int* __restrict__ src, const int* __restrict__ dst,
                 const unsigned short* __restrict__ wsw,
                 float* __restrict__ out) {
    __shared__ unsigned short wlds[32 * 512];      // 32   KB weights (frag order)
    __shared__ unsigned short rbf_lds[64 * 104];   // 13.3 KB bf16, row stride 208B
    __shared__ unsigned short ef_lds[64 * 64];     //  8   KB bf16, XOR-swizzled
    __shared__ unsigned short sp_lds[4 * 16 * 64]; //  8   KB softplus transpose

    const int tid = threadIdx.x;
    const int lane = tid & 63, wid = tid >> 6;     // wid in [0,4)
    const int l15 = lane & 15, g = lane >> 4;
    const long e0 = (long)blockIdx.x * 64;
    const int ew0 = (int)e0 + wid * 16;
    const int swz = (l15 & 7) << 3;

    // ---- index loads (needed by gathers/epilogue) ----
    const int4 s4 = *(const int4*)(src + ew0 + 4 * g);
    const int4 d4 = *(const int4*)(dst + ew0 + 4 * g);

    // ---- stage weights to LDS (8 uint4/thread, dense) ----
    {
        const uint4* wg = (const uint4*)wsw;
        uint4* wl = (uint4*)wlds;
#pragma unroll
        for (int i = 0; i < 8; ++i) wl[tid + 256 * i] = wg[tid + 256 * i];
    }

    // ---- stage rbf tile: 64 rows x 100 f32 = dense 25.6 KB span ----
    // f32x4 idx4 -> row = idx4/25, q = idx4%25 -> LDS ushort row*104 + 4q
    {
        const f32x4* rg = (const f32x4*)(rbf + e0 * RBF_DIM);
#pragma unroll
        for (int i = 0; i < 6; ++i) {
            int idx4 = tid + 256 * i;
            f32x4 v = rg[idx4];
            int row = idx4 / 25, q = idx4 - row * 25;
            *(uint2*)&rbf_lds[row * 104 + 4 * q] =
                make_uint2(cvtpk(v[0], v[1]), cvtpk(v[2], v[3]));
        }
        if (tid < 64) {
            int idx4 = tid + 1536;
            f32x4 v = rg[idx4];
            int row = idx4 / 25, q = idx4 - row * 25;
            *(uint2*)&rbf_lds[row * 104 + 4 * q] =
                make_uint2(cvtpk(v[0], v[1]), cvtpk(v[2], v[3]));
        }
    }
    // ---- stage ef tile: 64 x 64 f32 dense 16 KB span, XOR-swizzled bf16 ----
    {
        const f32x4* eg4 = (const f32x4*)(edge_f + e0 * 64);
#pragma unroll
        for (int i = 0; i < 4; ++i) {
            int idx4 = tid + 256 * i;
            f32x4 v = eg4[idx4];
            int row = idx4 >> 4, c = (idx4 & 15) * 4;
            int cs = c ^ ((row & 7) << 3);
            *(uint2*)&ef_lds[row * 64 + cs] =
                make_uint2(cvtpk(v[0], v[1]), cvtpk(v[2], v[3]));
        }
    }

    // ---- node gathers + biases (issue before barrier; consumed at epilogue) ----
    const int sv[4] = {s4.x, s4.y, s4.z, s4.w};
    const int dv[4] = {d4.x, d4.y, d4.z, d4.w};
    float nd[4][4];
#pragma unroll
    for (int r = 0; r < 4; ++r)
#pragma unroll
        for (int t4 = 0; t4 < 4; ++t4)
            nd[r][t4] = node[(long)sv[r] * 64 + 16 * t4 + l15];
    float b2v[4], b3v[4];
#pragma unroll
    for (int t4 = 0; t4 < 4; ++t4) { b2v[t4] = b2[16 * t4 + l15]; b3v[t4] = b3[16 * t4 + l15]; }

    __syncthreads();   // tiles + weights visible

    const bf16x8* frg = (const bf16x8*)wlds;
    const int erow = wid * 16 + l15;               // this lane's edge row in tile

    // ---- GEMM1: D1[d][e] = W1T @ rbf^T, B-frags from rbf_lds ----
    bf16x8 bfk[4];
#pragma unroll
    for (int ks = 0; ks < 3; ++ks)
        bfk[ks] = *(const bf16x8*)&rbf_lds[erow * 104 + 32 * ks + 8 * g];
    {
        // ks=3: k=96..99 from LDS tail + bias-1.0 at k=100 (g==0 only)
        uint2 t = *(const uint2*)&rbf_lds[erow * 104 + 96];
        union { bf16x8 v; unsigned int u[4]; } bt;
        bt.u[0] = (g == 0) ? t.x : 0u;
        bt.u[1] = (g == 0) ? t.y : 0u;
        bt.u[2] = (g == 0) ? 0x3F80u : 0u;
        bt.u[3] = 0u;
        bfk[3] = bt.v;
    }
    f32x4 acc1[4];
#pragma unroll
    for (int t4 = 0; t4 < 4; ++t4) acc1[t4] = (f32x4){0.f, 0.f, 0.f, 0.f};
#pragma unroll
    for (int ks = 0; ks < 4; ++ks)
#pragma unroll
        for (int t4 = 0; t4 < 4; ++t4)
            acc1[t4] = __builtin_amdgcn_mfma_f32_16x16x32_bf16(frg[(t4 * 4 + ks) * 64 + lane],
                                                               bfk[ks], acc1[t4], 0, 0, 0);

    // ---- softplus(beta=0.5, thr=14) -> sp_lds (own-wave region, no barrier) ----
    // D1 layout: lane (g,l15) holds col e=l15, rows d = 16*t4 + 4*g + r
#pragma unroll
    for (int t4 = 0; t4 < 4; ++t4) {
        float spv[4];
#pragma unroll
        for (int r = 0; r < 4; ++r) {
            float x = acc1[t4][r];
            float bx = 0.5f * x;
            float s = 2.0f * __logf(1.0f + __expf(bx));
            spv[r] = (bx > 14.0f) ? x : s;
        }
        unsigned int p0 = cvtpk(spv[0], spv[1]);
        unsigned int p1 = cvtpk(spv[2], spv[3]);
        int el = (wid * 16 + l15) * 64 + ((16 * t4 + 4 * g) ^ swz);
        *(uint2*)&sp_lds[el] = make_uint2(p0, p1);
    }

    // ---- GEMM2/3 swapped operands: D[e][d] edge-major; A-frags from LDS ----
    f32x4 acc2[4], acc3[4];
#pragma unroll
    for (int t4 = 0; t4 < 4; ++t4) {
        acc2[t4] = (f32x4){0.f, 0.f, 0.f, 0.f};
        acc3[t4] = (f32x4){0.f, 0.f, 0.f, 0.f};
    }
#pragma unroll
    for (int ks = 0; ks < 2; ++ks) {
        bf16x8 asp = *(const bf16x8*)&sp_lds[(wid * 16 + l15) * 64 + ((32 * ks + 8 * g) ^ swz)];
        bf16x8 aef = *(const bf16x8*)&ef_lds[erow * 64 + ((32 * ks + 8 * g) ^ swz)];
#pragma unroll
        for (int t4 = 0; t4 < 4; ++t4) {
            acc2[t4] = __builtin_amdgcn_mfma_f32_16x16x32_bf16(asp,
                          frg[(16 + t4 * 2 + ks) * 64 + lane], acc2[t4], 0, 0, 0);
            acc3[t4] = __builtin_amdgcn_mfma_f32_16x16x32_bf16(aef,
                          frg[(24 + t4 * 2 + ks) * 64 + lane], acc3[t4], 0, 0, 0);
        }
    }
    // acc2/acc3: lane (g,l15) holds edge 4g+r, dim 16*t4+l15

    // ---- epilogue: contiguous-dim atomic scatter from accumulators ----
#pragma unroll
    for (int r = 0; r < 4; ++r) {
        float* orow = out + (long)dv[r] * 64 + l15;
#pragma unroll
        for (int t4 = 0; t4 < 4; ++t4) {
            float msg = nd[r][t4] * (acc2[t4][r] + b2v[t4]) + (acc3[t4][r] + b3v[t4]);
            atomicAdd(&orow[16 * t4], msg);
        }
    }
}

extern "C" void kernel_launch(void* const* d_in, const int* in_sizes, int n_in,
                              void* d_out, int out_size, void* d_ws, size_t ws_size,
                              hipStream_t stream) {
    const float* rbf    = (const float*)d_in[0];
    const float* edge_f = (const float*)d_in[1];
    const float* node   = (const float*)d_in[2];
    const float* W1     = (const float*)d_in[3];
    const float* b1     = (const float*)d_in[4];
    const float* W2     = (const float*)d_in[5];
    const float* b2     = (const float*)d_in[6];
    const float* W3     = (const float*)d_in[7];
    const float* b3     = (const float*)d_in[8];
    const int*   src    = (const int*)d_in[9];
    const int*   dst    = (const int*)d_in[10];
    float* out = (float*)d_out;
    unsigned short* ws = (unsigned short*)d_ws;

    const int E = in_sizes[9];              // 800000, divisible by 64

    hipMemsetAsync(d_out, 0, (size_t)out_size * sizeof(float), stream);
    prep_weights<<<1, 256, 0, stream>>>(W1, b1, W2, W3, ws);
    veconv_main<<<E / 64, 256, 0, stream>>>(rbf, edge_f, node, b2, b3, src, dst, ws, out);
}

// Round 12
// 254.813 us; speedup vs baseline: 1.0098x; 1.0098x over previous
//
#include <hip/hip_runtime.h>

// VEConv: E=800000, N=50000, RBF=100, D=64. E % 256 == 0 (3125 blocks).
// Round 11b (r11 minus dead-code compile error): memory-issue-density attack.
// Six variants all pinned at ~2.4-2.56 TB/s effective while memset/copy hit
// 6.3-6.8; aggregate demand = waves/CU x bytes-per-wave / wave-wall matches
// the plateau -> waves don't ask for bytes often enough. Each wave owns TWO
// contiguous 16-edge subtiles (A,B). All 26 stream loads issue up-front (2x
// bytes in flight), both subtiles convert to bf16 (frees f32 regs), then
// compute+epilogue A, compute+epilogue B. launch_bounds(512,4) pins VGPR<=128
// so residency stays 16 waves/CU = r7's -- isolating the density variable.
// LDS 64 KB (32K weights + 32K sp) -> 2 blocks/CU.
#define RBF_DIM 100

typedef __attribute__((ext_vector_type(8))) short bf16x8;
typedef __attribute__((ext_vector_type(4))) float f32x4;

__device__ __forceinline__ unsigned short f2bf_sw(float f) {
    union { float f; unsigned int u; } v; v.f = f;
    unsigned int r = (v.u + 0x7FFFu + ((v.u >> 16) & 1u)) >> 16;
    return (unsigned short)r;
}
// hardware packed cvt: lo16 = bf16(x), hi16 = bf16(y), RNE
__device__ __forceinline__ unsigned int cvtpk(float x, float y) {
    unsigned int r;
    asm("v_cvt_pk_bf16_f32 %0, %1, %2" : "=v"(r) : "v"(x), "v"(y));
    return r;
}
__device__ __forceinline__ bf16x8 cvt8(f32x4 a, f32x4 b) {
    union { bf16x8 v; unsigned int u[4]; } r;
    r.u[0] = cvtpk(a[0], a[1]);
    r.u[1] = cvtpk(a[2], a[3]);
    r.u[2] = cvtpk(b[0], b[1]);
    r.u[3] = cvtpk(b[2], b[3]);
    return r.v;
}

// ---- pre-kernel: weights as bf16 MFMA fragments, dump order ----
// ws ushort layout: 32 frags x 64 lanes x 8 elems
//   f in [0,16):  W1T frag (t4=f>>2, ks=f&3), k=32ks+8g+j (k=100 -> b1, >100 -> 0)
//   f in [16,24): W2T frag (t4=(f-16)>>1, ks=(f-16)&1)
//   f in [24,32): W3T frag (t4=(f-24)>>1, ks=(f-24)&1)
__global__ void prep_weights(const float* __restrict__ W1, const float* __restrict__ b1,
                             const float* __restrict__ W2, const float* __restrict__ W3,
                             unsigned short* __restrict__ ws) {
    for (int e = threadIdx.x; e < 32 * 64 * 8; e += 256) {
        int f = e >> 9;
        int lane = (e >> 3) & 63;
        int j = e & 7;
        int l15 = lane & 15, g = lane >> 4;
        float v;
        if (f < 16) {
            int t4 = f >> 2, ks = f & 3;
            int k = 32 * ks + 8 * g + j, o = 16 * t4 + l15;
            v = (k < RBF_DIM) ? W1[k * 64 + o] : ((k == RBF_DIM) ? b1[o] : 0.0f);
        } else if (f < 24) {
            int q = f - 16, t4 = q >> 1, ks = q & 1;
            int k = 32 * ks + 8 * g + j, o = 16 * t4 + l15;
            v = W2[k * 64 + o];
        } else {
            int q = f - 24, t4 = q >> 1, ks = q & 1;
            int k = 32 * ks + 8 * g + j, o = 16 * t4 + l15;
            v = W3[k * 64 + o];
        }
        ws[e] = f2bf_sw(v);
    }
}

// ---- main fused kernel: 256 edges/block, 8 waves x 2 subtiles x 16 edges ----
__global__ __launch_bounds__(512, 4)
void veconv_main(const float* __restrict__ rbf, const float* __restrict__ edge_f,
                 const float* __restrict__ node,
                 const float* __restrict__ b2, const float* __restrict__ b3,
                 const int* __restrict__ src, const int* __restrict__ dst,
                 const unsigned short* __restrict__ wsw,
                 float* __restrict__ out) {
    __shared__ unsigned short wlds[32 * 512];      // 32 KB fragment-ordered weights
    __shared__ unsigned short sp_lds[8 * 32 * 64]; // 32 KB softplus (2 subtiles/wave)

    const int tid = threadIdx.x;
    const int lane = tid & 63, wid = tid >> 6;     // wid in [0,8)
    const int l15 = lane & 15, g = lane >> 4;
    const int ewA = blockIdx.x * 256 + wid * 32;   // subtile A first edge
    const int ewB = ewA + 16;
    const int egA = ewA + l15, egB = ewB + l15;
    const int swz = (l15 & 7) << 3;

    // ---- burst-issue ALL stream loads for BOTH subtiles ----
    const int4 s4A = *(const int4*)(src + ewA + 4 * g);
    const int4 d4A = *(const int4*)(dst + ewA + 4 * g);
    const int4 s4B = *(const int4*)(src + ewB + 4 * g);
    const int4 d4B = *(const int4*)(dst + ewB + 4 * g);

    const float* rrA = rbf + (long)egA * RBF_DIM;
    const f32x4 rA0 = *(const f32x4*)(rrA + 8 * g);
    const f32x4 rA1 = *(const f32x4*)(rrA + 8 * g + 4);
    const f32x4 rA2 = *(const f32x4*)(rrA + 32 + 8 * g);
    const f32x4 rA3 = *(const f32x4*)(rrA + 32 + 8 * g + 4);
    const f32x4 rA4 = *(const f32x4*)(rrA + 64 + 8 * g);
    const f32x4 rA5 = *(const f32x4*)(rrA + 64 + 8 * g + 4);
    f32x4 rtA = (f32x4){0.f, 0.f, 0.f, 0.f};
    if (g == 0) rtA = *(const f32x4*)(rrA + 96);

    const float* rrB = rbf + (long)egB * RBF_DIM;
    const f32x4 rB0 = *(const f32x4*)(rrB + 8 * g);
    const f32x4 rB1 = *(const f32x4*)(rrB + 8 * g + 4);
    const f32x4 rB2 = *(const f32x4*)(rrB + 32 + 8 * g);
    const f32x4 rB3 = *(const f32x4*)(rrB + 32 + 8 * g + 4);
    const f32x4 rB4 = *(const f32x4*)(rrB + 64 + 8 * g);
    const f32x4 rB5 = *(const f32x4*)(rrB + 64 + 8 * g + 4);
    f32x4 rtB = (f32x4){0.f, 0.f, 0.f, 0.f};
    if (g == 0) rtB = *(const f32x4*)(rrB + 96);

    const float* erA = edge_f + (long)egA * 64;
    const f32x4 eA0 = *(const f32x4*)(erA + 8 * g);
    const f32x4 eA1 = *(const f32x4*)(erA + 8 * g + 4);
    const f32x4 eA2 = *(const f32x4*)(erA + 32 + 8 * g);
    const f32x4 eA3 = *(const f32x4*)(erA + 32 + 8 * g + 4);
    const float* erB = edge_f + (long)egB * 64;
    const f32x4 eB0 = *(const f32x4*)(erB + 8 * g);
    const f32x4 eB1 = *(const f32x4*)(erB + 8 * g + 4);
    const f32x4 eB2 = *(const f32x4*)(erB + 32 + 8 * g);
    const f32x4 eB3 = *(const f32x4*)(erB + 32 + 8 * g + 4);

    // ---- stage weights to LDS (512 thr x 4 uint4, dense) ----
    {
        const uint4* wg = (const uint4*)wsw;
        uint4* wl = (uint4*)wlds;
#pragma unroll
        for (int i = 0; i < 4; ++i) wl[tid + 512 * i] = wg[tid + 512 * i];
    }
    float b2v[4], b3v[4];
#pragma unroll
    for (int t4 = 0; t4 < 4; ++t4) { b2v[t4] = b2[16 * t4 + l15]; b3v[t4] = b3[16 * t4 + l15]; }

    // ---- convert both subtiles to bf16 (frees the f32 staging regs) ----
    bf16x8 bfkA[4], bfkB[4], aeA[2], aeB[2];
    bfkA[0] = cvt8(rA0, rA1); bfkA[1] = cvt8(rA2, rA3); bfkA[2] = cvt8(rA4, rA5);
    bfkB[0] = cvt8(rB0, rB1); bfkB[1] = cvt8(rB2, rB3); bfkB[2] = cvt8(rB4, rB5);
    {
        union { bf16x8 v; unsigned int u[4]; } bt;
        bt.u[0] = (g == 0) ? cvtpk(rtA[0], rtA[1]) : 0u;
        bt.u[1] = (g == 0) ? cvtpk(rtA[2], rtA[3]) : 0u;
        bt.u[2] = (g == 0) ? 0x3F80u : 0u;   // k=100 bias-1.0 column
        bt.u[3] = 0u;
        bfkA[3] = bt.v;
        bt.u[0] = (g == 0) ? cvtpk(rtB[0], rtB[1]) : 0u;
        bt.u[1] = (g == 0) ? cvtpk(rtB[2], rtB[3]) : 0u;
        bt.u[2] = (g == 0) ? 0x3F80u : 0u;
        bt.u[3] = 0u;
        bfkB[3] = bt.v;
    }
    aeA[0] = cvt8(eA0, eA1); aeA[1] = cvt8(eA2, eA3);
    aeB[0] = cvt8(eB0, eB1); aeB[1] = cvt8(eB2, eB3);

    __syncthreads();   // weights visible to all waves

    const bf16x8* frg = (const bf16x8*)wlds;

    // ================= subtile A, then subtile B =================
#pragma unroll
    for (int sub = 0; sub < 2; ++sub) {
        const bf16x8* bfk = (sub == 0) ? bfkA : bfkB;
        const bf16x8* ae  = (sub == 0) ? aeA  : aeB;
        const int4 s4 = (sub == 0) ? s4A : s4B;
        const int4 d4 = (sub == 0) ? d4A : d4B;
        unsigned short* spb = sp_lds + (wid * 32 + sub * 16) * 64;

        // node gathers for this subtile (overlap with GEMM1 below)
        const int sv[4] = {s4.x, s4.y, s4.z, s4.w};
        const int dv[4] = {d4.x, d4.y, d4.z, d4.w};
        float nd[4][4];
#pragma unroll
        for (int r = 0; r < 4; ++r)
#pragma unroll
            for (int t4 = 0; t4 < 4; ++t4)
                nd[r][t4] = node[(long)sv[r] * 64 + 16 * t4 + l15];

        // GEMM1: D1[d][e] = W1T @ rbf^T
        f32x4 acc1[4];
#pragma unroll
        for (int t4 = 0; t4 < 4; ++t4) acc1[t4] = (f32x4){0.f, 0.f, 0.f, 0.f};
#pragma unroll
        for (int ks = 0; ks < 4; ++ks)
#pragma unroll
            for (int t4 = 0; t4 < 4; ++t4)
                acc1[t4] = __builtin_amdgcn_mfma_f32_16x16x32_bf16(
                    frg[(t4 * 4 + ks) * 64 + lane], bfk[ks], acc1[t4], 0, 0, 0);

        // softplus(beta=0.5, thr=14) -> sp (own-wave region, no barrier)
        // D1 layout: lane (g,l15) holds col e=l15, rows d = 16*t4 + 4*g + r
#pragma unroll
        for (int t4 = 0; t4 < 4; ++t4) {
            float spv[4];
#pragma unroll
            for (int r = 0; r < 4; ++r) {
                float x = acc1[t4][r];
                float bx = 0.5f * x;
                float s = 2.0f * __logf(1.0f + __expf(bx));
                spv[r] = (bx > 14.0f) ? x : s;
            }
            unsigned int p0 = cvtpk(spv[0], spv[1]);
            unsigned int p1 = cvtpk(spv[2], spv[3]);
            *(uint2*)&spb[l15 * 64 + ((16 * t4 + 4 * g) ^ swz)] = make_uint2(p0, p1);
        }

        // GEMM2/3 swapped operands: D[e][d] edge-major
        f32x4 acc2[4], acc3[4];
#pragma unroll
        for (int t4 = 0; t4 < 4; ++t4) {
            acc2[t4] = (f32x4){0.f, 0.f, 0.f, 0.f};
            acc3[t4] = (f32x4){0.f, 0.f, 0.f, 0.f};
        }
#pragma unroll
        for (int ks = 0; ks < 2; ++ks) {
            bf16x8 asp = *(const bf16x8*)&spb[l15 * 64 + ((32 * ks + 8 * g) ^ swz)];
#pragma unroll
            for (int t4 = 0; t4 < 4; ++t4) {
                acc2[t4] = __builtin_amdgcn_mfma_f32_16x16x32_bf16(asp,
                              frg[(16 + t4 * 2 + ks) * 64 + lane], acc2[t4], 0, 0, 0);
                acc3[t4] = __builtin_amdgcn_mfma_f32_16x16x32_bf16(ae[ks],
                              frg[(24 + t4 * 2 + ks) * 64 + lane], acc3[t4], 0, 0, 0);
            }
        }
        // acc2/acc3: lane (g,l15) holds edge 4g+r, dim 16*t4+l15

        // epilogue: contiguous-dim atomic scatter from accumulators
#pragma unroll
        for (int r = 0; r < 4; ++r) {
            float* orow = out + (long)dv[r] * 64 + l15;
#pragma unroll
            for (int t4 = 0; t4 < 4; ++t4) {
                float msg = nd[r][t4] * (acc2[t4][r] + b2v[t4]) + (acc3[t4][r] + b3v[t4]);
                atomicAdd(&orow[16 * t4], msg);
            }
        }
    }
}

extern "C" void kernel_launch(void* const* d_in, const int* in_sizes, int n_in,
                              void* d_out, int out_size, void* d_ws, size_t ws_size,
                              hipStream_t stream) {
    const float* rbf    = (const float*)d_in[0];
    const float* edge_f = (const float*)d_in[1];
    const float* node   = (const float*)d_in[2];
    const float* W1     = (const float*)d_in[3];
    const float* b1     = (const float*)d_in[4];
    const float* W2     = (const float*)d_in[5];
    const float* b2     = (const float*)d_in[6];
    const float* W3     = (const float*)d_in[7];
    const float* b3     = (const float*)d_in[8];
    const int*   src    = (const int*)d_in[9];
    const int*   dst    = (const int*)d_in[10];
    float* out = (float*)d_out;
    unsigned short* ws = (unsigned short*)d_ws;

    const int E = in_sizes[9];              // 800000, divisible by 256

    (void)hipMemsetAsync(d_out, 0, (size_t)out_size * sizeof(float), stream);
    prep_weights<<<1, 256, 0, stream>>>(W1, b1, W2, W3, ws);
    veconv_main<<<E / 256, 512, 0, stream>>>(rbf, edge_f, node, b2, b3, src, dst, ws, out);
}

// Round 13
// 230.557 us; speedup vs baseline: 1.1160x; 1.1052x over previous
//
#include <hip/hip_runtime.h>

// VEConv: E=800000, N=50000, RBF=100, D=64.
// Round 13: async DMA staging (global_load_lds) -- the untried lever.
// All VGPR-staged designs collapse to ~4-8 outstanding loads/wave (compiler
// balances VGPR vs in-flight) -> ~2.5 TB/s aggregate. global_load_lds is
// fire-and-forget: no VGPRs, vmcnt-queued, drained by the end-of-iteration
// barrier a full compute phase after issue.
//   - 512-thr blocks, 128-edge tiles, NT=5 contiguous tiles/block (grid 1250)
//   - rbf tile (51200 B f32) DMA'd into double-buffered LDS; prefetch 1 tile
//   - weights in LDS (32 KB, r5 win); ef/node/src/dst direct (L3-resident/small)
//   - r7 swapped-GEMM2/3 + contiguous-dim atomic epilogue
//   - LDS 148 KB -> 1 block/CU, 8 waves (MLP from DMA queue, not TLP)
#define RBF_DIM 100
#define NT 5

typedef __attribute__((ext_vector_type(8))) short bf16x8;
typedef __attribute__((ext_vector_type(4))) float f32x4;

__device__ __forceinline__ unsigned short f2bf_sw(float f) {
    union { float f; unsigned int u; } v; v.f = f;
    unsigned int r = (v.u + 0x7FFFu + ((v.u >> 16) & 1u)) >> 16;
    return (unsigned short)r;
}
// hardware packed cvt: lo16 = bf16(x), hi16 = bf16(y), RNE
__device__ __forceinline__ unsigned int cvtpk(float x, float y) {
    unsigned int r;
    asm("v_cvt_pk_bf16_f32 %0, %1, %2" : "=v"(r) : "v"(x), "v"(y));
    return r;
}
__device__ __forceinline__ bf16x8 cvt8(f32x4 a, f32x4 b) {
    union { bf16x8 v; unsigned int u[4]; } r;
    r.u[0] = cvtpk(a[0], a[1]);
    r.u[1] = cvtpk(a[2], a[3]);
    r.u[2] = cvtpk(b[0], b[1]);
    r.u[3] = cvtpk(b[2], b[3]);
    return r.v;
}
// async global->LDS, 16 B per lane; LDS dest = wave-uniform base + lane*16
__device__ __forceinline__ void dma16(const float* g, void* l) {
    __builtin_amdgcn_global_load_lds((const __attribute__((address_space(1))) void*)g,
                                     (__attribute__((address_space(3))) void*)l, 16, 0, 0);
}

// ---- pre-kernel: weights as bf16 MFMA fragments, dump order ----
__global__ void prep_weights(const float* __restrict__ W1, const float* __restrict__ b1,
                             const float* __restrict__ W2, const float* __restrict__ W3,
                             unsigned short* __restrict__ ws) {
    for (int e = threadIdx.x; e < 32 * 64 * 8; e += 256) {
        int f = e >> 9;
        int lane = (e >> 3) & 63;
        int j = e & 7;
        int l15 = lane & 15, g = lane >> 4;
        float v;
        if (f < 16) {
            int t4 = f >> 2, ks = f & 3;
            int k = 32 * ks + 8 * g + j, o = 16 * t4 + l15;
            v = (k < RBF_DIM) ? W1[k * 64 + o] : ((k == RBF_DIM) ? b1[o] : 0.0f);
        } else if (f < 24) {
            int q = f - 16, t4 = q >> 1, ks = q & 1;
            int k = 32 * ks + 8 * g + j, o = 16 * t4 + l15;
            v = W2[k * 64 + o];
        } else {
            int q = f - 24, t4 = q >> 1, ks = q & 1;
            int k = 32 * ks + 8 * g + j, o = 16 * t4 + l15;
            v = W3[k * 64 + o];
        }
        ws[e] = f2bf_sw(v);
    }
}

// ---- main: 128-edge tiles, NT tiles/block, DMA double-buffered rbf ----
__global__ __launch_bounds__(512, 2)
void veconv_main(const float* __restrict__ rbf, const float* __restrict__ edge_f,
                 const float* __restrict__ node,
                 const float* __restrict__ b2, const float* __restrict__ b3,
                 const int* __restrict__ src, const int* __restrict__ dst,
                 const unsigned short* __restrict__ wsw,
                 float* __restrict__ out, int ntiles) {
    __shared__ unsigned short wlds[32 * 512];      // 32 KB fragment-ordered weights
    __shared__ float rbuf[2][128 * 100];           // 2 x 50 KB raw-f32 rbf tiles
    __shared__ unsigned short sp_lds[8 * 16 * 64]; // 16 KB softplus (per-wave)

    const int tid = threadIdx.x;
    const int lane = tid & 63, wid = tid >> 6;     // wid in [0,8)
    const int l15 = lane & 15, g = lane >> 4;
    const int swz = (l15 & 7) << 3;
    const long tile0 = (long)blockIdx.x * NT;

    // ---- stage weights to LDS (dense, once) ----
    {
        const uint4* wg = (const uint4*)wsw;
        uint4* wl = (uint4*)wlds;
#pragma unroll
        for (int i = 0; i < 4; ++i) wl[tid + 512 * i] = wg[tid + 512 * i];
    }
    float b2v[4], b3v[4];
#pragma unroll
    for (int t4 = 0; t4 < 4; ++t4) { b2v[t4] = b2[16 * t4 + l15]; b3v[t4] = b3[16 * t4 + l15]; }

    // ---- DMA rbf tile0 -> rbuf[0] (50 x 1KB chunks; wave w takes c=w,w+8,..) ----
    {
        const float* gt = rbf + tile0 * 128 * RBF_DIM;
        for (int c = wid; c < 50; c += 8)
            dma16(gt + c * 256 + lane * 4, (char*)&rbuf[0][0] + c * 1024);
    }
    __syncthreads();   // weights + tile0 visible

    const bf16x8* frg = (const bf16x8*)wlds;

    for (int i = 0; i < NT; ++i) {
        const long tile = tile0 + i;
        if (tile >= ntiles) break;             // block-uniform
        const int cur = i & 1;

        // ---- issue DMA for tile i+1 (fire-and-forget; drained at barrier) ----
        if (i + 1 < NT && tile + 1 < ntiles) {
            const float* gt = rbf + (tile + 1) * 128 * RBF_DIM;
            for (int c = wid; c < 50; c += 8)
                dma16(gt + c * 256 + lane * 4, (char*)&rbuf[cur ^ 1][0] + c * 1024);
        }

        // ---- direct loads for this tile ----
        const int ew0 = (int)(tile * 128) + wid * 16;
        const int eg = ew0 + l15;
        const int4 s4 = *(const int4*)(src + ew0 + 4 * g);
        const int4 d4 = *(const int4*)(dst + ew0 + 4 * g);
        const float* erow = edge_f + (long)eg * 64;
        const f32x4 ea0 = *(const f32x4*)(erow + 8 * g);
        const f32x4 ea1 = *(const f32x4*)(erow + 8 * g + 4);
        const f32x4 eb0 = *(const f32x4*)(erow + 32 + 8 * g);
        const f32x4 eb1 = *(const f32x4*)(erow + 32 + 8 * g + 4);
        const int sv[4] = {s4.x, s4.y, s4.z, s4.w};
        const int dv[4] = {d4.x, d4.y, d4.z, d4.w};
        float nd[4][4];
#pragma unroll
        for (int r = 0; r < 4; ++r)
#pragma unroll
            for (int t4 = 0; t4 < 4; ++t4)
                nd[r][t4] = node[(long)sv[r] * 64 + 16 * t4 + l15];

        // ---- GEMM1: B-frags from LDS rbf (f32 -> cvt_pk -> bf16) ----
        const float* rrow = &rbuf[cur][(wid * 16 + l15) * RBF_DIM];
        bf16x8 bfk[4];
#pragma unroll
        for (int ks = 0; ks < 3; ++ks) {
            f32x4 a = *(const f32x4*)(rrow + 32 * ks + 8 * g);
            f32x4 b = *(const f32x4*)(rrow + 32 * ks + 8 * g + 4);
            bfk[ks] = cvt8(a, b);
        }
        {
            f32x4 t = (g == 0) ? *(const f32x4*)(rrow + 96) : (f32x4){0.f, 0.f, 0.f, 0.f};
            union { bf16x8 v; unsigned int u[4]; } bt;
            bt.u[0] = (g == 0) ? cvtpk(t[0], t[1]) : 0u;
            bt.u[1] = (g == 0) ? cvtpk(t[2], t[3]) : 0u;
            bt.u[2] = (g == 0) ? 0x3F80u : 0u;   // k=100 bias-1.0 column
            bt.u[3] = 0u;
            bfk[3] = bt.v;
        }
        f32x4 acc1[4];
#pragma unroll
        for (int t4 = 0; t4 < 4; ++t4) acc1[t4] = (f32x4){0.f, 0.f, 0.f, 0.f};
#pragma unroll
        for (int ks = 0; ks < 4; ++ks)
#pragma unroll
            for (int t4 = 0; t4 < 4; ++t4)
                acc1[t4] = __builtin_amdgcn_mfma_f32_16x16x32_bf16(
                    frg[(t4 * 4 + ks) * 64 + lane], bfk[ks], acc1[t4], 0, 0, 0);

        // ---- softplus(beta=0.5, thr=14) -> sp_lds (own-wave region) ----
        // D1 layout: lane (g,l15) holds col e=l15, rows d = 16*t4 + 4*g + r
#pragma unroll
        for (int t4 = 0; t4 < 4; ++t4) {
            float spv[4];
#pragma unroll
            for (int r = 0; r < 4; ++r) {
                float x = acc1[t4][r];
                float bx = 0.5f * x;
                float s = 2.0f * __logf(1.0f + __expf(bx));
                spv[r] = (bx > 14.0f) ? x : s;
            }
            unsigned int p0 = cvtpk(spv[0], spv[1]);
            unsigned int p1 = cvtpk(spv[2], spv[3]);
            int el = (wid * 16 + l15) * 64 + ((16 * t4 + 4 * g) ^ swz);
            *(uint2*)&sp_lds[el] = make_uint2(p0, p1);
        }

        // ---- GEMM2/3 swapped operands: D[e][d] edge-major ----
        bf16x8 aef[2];
        aef[0] = cvt8(ea0, ea1);
        aef[1] = cvt8(eb0, eb1);
        f32x4 acc2[4], acc3[4];
#pragma unroll
        for (int t4 = 0; t4 < 4; ++t4) {
            acc2[t4] = (f32x4){0.f, 0.f, 0.f, 0.f};
            acc3[t4] = (f32x4){0.f, 0.f, 0.f, 0.f};
        }
#pragma unroll
        for (int ks = 0; ks < 2; ++ks) {
            bf16x8 asp = *(const bf16x8*)&sp_lds[(wid * 16 + l15) * 64 + ((32 * ks + 8 * g) ^ swz)];
#pragma unroll
            for (int t4 = 0; t4 < 4; ++t4) {
                acc2[t4] = __builtin_amdgcn_mfma_f32_16x16x32_bf16(asp,
                              frg[(16 + t4 * 2 + ks) * 64 + lane], acc2[t4], 0, 0, 0);
                acc3[t4] = __builtin_amdgcn_mfma_f32_16x16x32_bf16(aef[ks],
                              frg[(24 + t4 * 2 + ks) * 64 + lane], acc3[t4], 0, 0, 0);
            }
        }
        // acc2/acc3: lane (g,l15) holds edge 4g+r, dim 16*t4+l15

        // ---- epilogue: contiguous-dim atomic scatter ----
#pragma unroll
        for (int r = 0; r < 4; ++r) {
            float* orow = out + (long)dv[r] * 64 + l15;
#pragma unroll
            for (int t4 = 0; t4 < 4; ++t4) {
                float msg = nd[r][t4] * (acc2[t4][r] + b2v[t4]) + (acc3[t4][r] + b3v[t4]);
                atomicAdd(&orow[16 * t4], msg);
            }
        }

        // drain DMA (arrived during compute) + protect rbuf[cur] reuse
        __syncthreads();
    }
}

extern "C" void kernel_launch(void* const* d_in, const int* in_sizes, int n_in,
                              void* d_out, int out_size, void* d_ws, size_t ws_size,
                              hipStream_t stream) {
    const float* rbf    = (const float*)d_in[0];
    const float* edge_f = (const float*)d_in[1];
    const float* node   = (const float*)d_in[2];
    const float* W1     = (const float*)d_in[3];
    const float* b1     = (const float*)d_in[4];
    const float* W2     = (const float*)d_in[5];
    const float* b2     = (const float*)d_in[6];
    const float* W3     = (const float*)d_in[7];
    const float* b3     = (const float*)d_in[8];
    const int*   src    = (const int*)d_in[9];
    const int*   dst    = (const int*)d_in[10];
    float* out = (float*)d_out;
    unsigned short* ws = (unsigned short*)d_ws;

    const int E = in_sizes[9];               // 800000, divisible by 128
    const int ntiles = E / 128;              // 6250
    const int grid = (ntiles + NT - 1) / NT; // 1250

    (void)hipMemsetAsync(d_out, 0, (size_t)out_size * sizeof(float), stream);
    prep_weights<<<1, 256, 0, stream>>>(W1, b1, W2, W3, ws);
    veconv_main<<<grid, 512, 0, stream>>>(rbf, edge_f, node, b2, b3, src, dst, ws, out, ntiles);
}